// Round 1
// baseline (922.639 us; speedup 1.0000x reference)
//
#include <hip/hip_runtime.h>

#define F_IN 64
#define HD 32
#define NCLS 2
#define BN_EPS 1e-5f

// ---------- degree + histogram (by target col) ----------
__global__ void deg_hist_kernel(const int* __restrict__ ei, const float* __restrict__ w,
                                float* __restrict__ deg, int* __restrict__ counts, int E) {
    int e = blockIdx.x * blockDim.x + threadIdx.x;
    if (e >= E) return;
    int c = ei[E + e];
    atomicAdd(&deg[c], w[e]);
    atomicAdd(&counts[c], 1);
}

// ---------- dis = rsqrt(deg + 1)  (self-loop weight 1 included) ----------
__global__ void dis_kernel(const float* __restrict__ deg, float* __restrict__ dis, int n) {
    int i = blockIdx.x * blockDim.x + threadIdx.x;
    if (i >= n) return;
    float d = deg[i] + 1.0f;   // self-loop contributes weight 1; d >= 1 > 0
    dis[i] = rsqrtf(d);
}

// ---------- single-block exclusive scan over counts -> offsets, cursor ----------
__global__ void scan_kernel(const int* __restrict__ counts, int* __restrict__ offs,
                            int* __restrict__ cursor, int n) {
    __shared__ int lds[1024];
    __shared__ int carry;
    int tid = threadIdx.x;
    if (tid == 0) carry = 0;
    __syncthreads();
    for (int base = 0; base < n; base += 1024) {
        int i = base + tid;
        int v = (i < n) ? counts[i] : 0;
        lds[tid] = v;
        __syncthreads();
        for (int off = 1; off < 1024; off <<= 1) {
            int t = (tid >= off) ? lds[tid - off] : 0;
            __syncthreads();
            lds[tid] += t;
            __syncthreads();
        }
        int excl = lds[tid] - v;
        if (i < n) { offs[i] = carry + excl; cursor[i] = carry + excl; }
        __syncthreads();
        if (tid == 0) carry += lds[1023];
        __syncthreads();
    }
    if (tid == 0) offs[n] = carry;
}

// ---------- fill CSR: (row, norm) bucketed by col ----------
__global__ void fill_kernel(const int* __restrict__ ei, const float* __restrict__ w,
                            const float* __restrict__ dis, int* __restrict__ cursor,
                            int* __restrict__ crow, float* __restrict__ cnorm, int E) {
    int e = blockIdx.x * blockDim.x + threadIdx.x;
    if (e >= E) return;
    int r = ei[e], c = ei[E + e];
    float nw = dis[r] * w[e] * dis[c];
    int pos = atomicAdd(&cursor[c], 1);
    crow[pos] = r;
    cnorm[pos] = nw;
}

// ---------- small GEMM: Hout[N,32] = X[N,FIN] @ W[FIN,32]; also zeroes stats ----------
template <int FIN>
__global__ void gemm_kernel(const float* __restrict__ X, const float* __restrict__ W,
                            float* __restrict__ Hout, float* __restrict__ stats, int n) {
    __shared__ float Wl[FIN * HD];
    for (int i = threadIdx.x; i < FIN * HD; i += blockDim.x) Wl[i] = W[i];
    if (blockIdx.x == 0 && threadIdx.x < 64) stats[threadIdx.x] = 0.0f;
    __syncthreads();
    int idx = blockIdx.x * blockDim.x + threadIdx.x;
    if (idx >= n * HD) return;
    int node = idx >> 5, h = idx & 31;
    const float* xr = X + (size_t)node * FIN;
    float acc = 0.0f;
#pragma unroll
    for (int k = 0; k < FIN; k++) acc += xr[k] * Wl[k * HD + h];
    Hout[idx] = acc;
}

// ---------- aggregate: y[c] = relu(b + sum_{e: col==c} hlin[row]*norm + hlin[c]*dis[c]^2)
// one wave per node (32 lanes = feature dim, 2 edges in flight), + BN stats ----------
#define NODES_PER_WAVE 16
__global__ void agg_kernel(const float* __restrict__ hlin, const int* __restrict__ offs,
                           const int* __restrict__ crow, const float* __restrict__ cnorm,
                           const float* __restrict__ dis, const float* __restrict__ bias,
                           float* __restrict__ y, float* __restrict__ stats, int n) {
    int wave = threadIdx.x >> 6, lane = threadIdx.x & 63, sub = lane >> 5, h = lane & 31;
    float lsum = 0.0f, lsq = 0.0f;
    int base = (blockIdx.x * 4 + wave) * NODES_PER_WAVE;
    for (int t = 0; t < NODES_PER_WAVE; t++) {
        int node = base + t;
        if (node < n) {
            int s = offs[node], e2 = offs[node + 1];
            float acc = 0.0f;
            if (sub == 0) {
                float d = dis[node];
                acc = hlin[(size_t)node * HD + h] * d * d;   // self-loop
            }
            for (int j = s + sub; j < e2; j += 2) {
                acc += hlin[(size_t)crow[j] * HD + h] * cnorm[j];
            }
            acc += __shfl_xor(acc, 32, 64);
            float yv = fmaxf(acc + bias[h], 0.0f);
            if (sub == 0) {
                y[(size_t)node * HD + h] = yv;
                lsum += yv; lsq += yv * yv;
            }
        }
    }
    __shared__ float ls[4][32], lq[4][32];
    if (sub == 0) { ls[wave][h] = lsum; lq[wave][h] = lsq; }
    __syncthreads();
    if (threadIdx.x < 32) {
        float a = ls[0][threadIdx.x] + ls[1][threadIdx.x] + ls[2][threadIdx.x] + ls[3][threadIdx.x];
        float b = lq[0][threadIdx.x] + lq[1][threadIdx.x] + lq[2][threadIdx.x] + lq[3][threadIdx.x];
        atomicAdd(&stats[threadIdx.x], a);
        atomicAdd(&stats[32 + threadIdx.x], b);
    }
}

// ---------- BN params: scale/shift from sums ----------
__global__ void bnparam_kernel(const float* __restrict__ stats, const float* __restrict__ g,
                               const float* __restrict__ be, float* __restrict__ sc, int n) {
    int h = threadIdx.x;
    if (h >= HD) return;
    float invn = 1.0f / (float)n;
    float mean = stats[h] * invn;
    float var = stats[32 + h] * invn - mean * mean;   // biased variance
    float inv = rsqrtf(var + BN_EPS);
    float scale = inv * g[h];
    sc[h] = scale;
    sc[32 + h] = be[h] - mean * scale;
}

// ---------- BN apply ----------
__global__ void bn_apply_kernel(const float* __restrict__ y, const float* __restrict__ sc,
                                float* __restrict__ out, int total) {
    int idx = blockIdx.x * blockDim.x + threadIdx.x;
    if (idx >= total) return;
    int h = idx & 31;
    out[idx] = y[idx] * sc[h] + sc[32 + h];
}

// ---------- final linear: [N,96] @ [96,2] + bl ----------
__global__ void final_kernel(const float* __restrict__ o1, const float* __restrict__ o2,
                             const float* __restrict__ o3, const float* __restrict__ Wl,
                             const float* __restrict__ bl, float* __restrict__ out, int n) {
    __shared__ float Ws[96 * NCLS];
    __shared__ float bs[NCLS];
    for (int i = threadIdx.x; i < 96 * NCLS; i += blockDim.x) Ws[i] = Wl[i];
    if (threadIdx.x < NCLS) bs[threadIdx.x] = bl[threadIdx.x];
    __syncthreads();
    int i = blockIdx.x * blockDim.x + threadIdx.x;
    if (i >= n) return;
    float a0 = bs[0], a1 = bs[1];
    const float* r1 = o1 + (size_t)i * HD;
    const float* r2 = o2 + (size_t)i * HD;
    const float* r3 = o3 + (size_t)i * HD;
#pragma unroll
    for (int k = 0; k < HD; k++) { float v = r1[k]; a0 += v * Ws[k * 2]; a1 += v * Ws[k * 2 + 1]; }
#pragma unroll
    for (int k = 0; k < HD; k++) { float v = r2[k]; a0 += v * Ws[(32 + k) * 2]; a1 += v * Ws[(32 + k) * 2 + 1]; }
#pragma unroll
    for (int k = 0; k < HD; k++) { float v = r3[k]; a0 += v * Ws[(64 + k) * 2]; a1 += v * Ws[(64 + k) * 2 + 1]; }
    out[(size_t)i * 2] = a0;
    out[(size_t)i * 2 + 1] = a1;
}

extern "C" void kernel_launch(void* const* d_in, const int* in_sizes, int n_in,
                              void* d_out, int out_size, void* d_ws, size_t ws_size,
                              hipStream_t stream) {
    const float* x  = (const float*)d_in[0];
    const int*   ei = (const int*)d_in[1];
    const float* ew = (const float*)d_in[2];
    const float* W1 = (const float*)d_in[3];  const float* b1  = (const float*)d_in[4];
    const float* g1 = (const float*)d_in[5];  const float* be1 = (const float*)d_in[6];
    const float* W2 = (const float*)d_in[7];  const float* b2  = (const float*)d_in[8];
    const float* g2 = (const float*)d_in[9];  const float* be2 = (const float*)d_in[10];
    const float* W3 = (const float*)d_in[11]; const float* b3  = (const float*)d_in[12];
    const float* g3 = (const float*)d_in[13]; const float* be3 = (const float*)d_in[14];
    const float* Wl = (const float*)d_in[15]; const float* bl  = (const float*)d_in[16];

    int n = in_sizes[0] / F_IN;
    int E = in_sizes[1] / 2;

    char* ws = (char*)d_ws;
    auto alloc = [&](size_t bytes) -> char* {
        char* p = ws;
        ws += (bytes + 255) / 256 * 256;
        return p;
    };
    float* deg    = (float*)alloc((size_t)n * 4);
    float* dis    = (float*)alloc((size_t)n * 4);
    int*   counts = (int*)alloc((size_t)n * 4);
    int*   offs   = (int*)alloc((size_t)(n + 1) * 4);
    int*   cursor = (int*)alloc((size_t)n * 4);
    int*   crow   = (int*)alloc((size_t)E * 4);
    float* cnorm  = (float*)alloc((size_t)E * 4);
    float* hlin   = (float*)alloc((size_t)n * HD * 4);
    float* ybuf   = (float*)alloc((size_t)n * HD * 4);
    float* o1     = (float*)alloc((size_t)n * HD * 4);
    float* o2     = (float*)alloc((size_t)n * HD * 4);
    float* o3     = (float*)alloc((size_t)n * HD * 4);
    float* stats  = (float*)alloc(64 * 4);
    float* sc     = (float*)alloc(64 * 4);

    hipMemsetAsync(deg, 0, (size_t)n * 4, stream);
    hipMemsetAsync(counts, 0, (size_t)n * 4, stream);

    int eb = (E + 255) / 256;
    int nb = (n + 255) / 256;
    int nhb = (n * HD + 255) / 256;
    int aggb = (n + 4 * NODES_PER_WAVE - 1) / (4 * NODES_PER_WAVE);

    deg_hist_kernel<<<eb, 256, 0, stream>>>(ei, ew, deg, counts, E);
    dis_kernel<<<nb, 256, 0, stream>>>(deg, dis, n);
    scan_kernel<<<1, 1024, 0, stream>>>(counts, offs, cursor, n);
    fill_kernel<<<eb, 256, 0, stream>>>(ei, ew, dis, cursor, crow, cnorm, E);

    // layer 1
    gemm_kernel<F_IN><<<nhb, 256, 0, stream>>>(x, W1, hlin, stats, n);
    agg_kernel<<<aggb, 256, 0, stream>>>(hlin, offs, crow, cnorm, dis, b1, ybuf, stats, n);
    bnparam_kernel<<<1, 32, 0, stream>>>(stats, g1, be1, sc, n);
    bn_apply_kernel<<<nhb, 256, 0, stream>>>(ybuf, sc, o1, n * HD);
    // layer 2
    gemm_kernel<HD><<<nhb, 256, 0, stream>>>(o1, W2, hlin, stats, n);
    agg_kernel<<<aggb, 256, 0, stream>>>(hlin, offs, crow, cnorm, dis, b2, ybuf, stats, n);
    bnparam_kernel<<<1, 32, 0, stream>>>(stats, g2, be2, sc, n);
    bn_apply_kernel<<<nhb, 256, 0, stream>>>(ybuf, sc, o2, n * HD);
    // layer 3
    gemm_kernel<HD><<<nhb, 256, 0, stream>>>(o2, W3, hlin, stats, n);
    agg_kernel<<<aggb, 256, 0, stream>>>(hlin, offs, crow, cnorm, dis, b3, ybuf, stats, n);
    bnparam_kernel<<<1, 32, 0, stream>>>(stats, g3, be3, sc, n);
    bn_apply_kernel<<<nhb, 256, 0, stream>>>(ybuf, sc, o3, n * HD);

    final_kernel<<<nb, 256, 0, stream>>>(o1, o2, o3, Wl, bl, (float*)d_out, n);
}

// Round 2
// 700.529 us; speedup vs baseline: 1.3171x; 1.3171x over previous
//
#include <hip/hip_runtime.h>

#define F_IN 64
#define HD 32
#define NCLS 2
#define BN_EPS 1e-5f
#define SCHUNK 1024
#define NODES_PER_WAVE 16

// ---------- degree + histogram (by target col) ----------
__global__ void deg_hist_kernel(const int* __restrict__ ei, const float* __restrict__ w,
                                float* __restrict__ deg, int* __restrict__ counts, int E) {
    int e = blockIdx.x * blockDim.x + threadIdx.x;
    if (e >= E) return;
    int c = ei[E + e];
    atomicAdd(&deg[c], w[e]);
    atomicAdd(&counts[c], 1);
}

// ---------- scan phase A: per-chunk sums; fused dis = rsqrt(deg+1) ----------
__global__ void scanA_kernel(const int* __restrict__ counts, const float* __restrict__ deg,
                             int* __restrict__ partial, float* __restrict__ dis, int n) {
    __shared__ int red[256];
    int base = blockIdx.x * SCHUNK;
    int tid = threadIdx.x;
    int s = 0;
    for (int i = tid; i < SCHUNK; i += 256) {
        int idx = base + i;
        if (idx < n) {
            s += counts[idx];
            dis[idx] = rsqrtf(deg[idx] + 1.0f);   // self-loop weight 1; d >= 1
        }
    }
    red[tid] = s;
    __syncthreads();
    for (int off = 128; off > 0; off >>= 1) {
        if (tid < off) red[tid] += red[tid + off];
        __syncthreads();
    }
    if (tid == 0) partial[blockIdx.x] = red[0];
}

// ---------- scan phase B: exclusive-scan the (<=256) partials; write total ----------
__global__ void scanB_kernel(int* __restrict__ partial, int nb, int* __restrict__ offs_n) {
    __shared__ int lds[256];
    int tid = threadIdx.x;
    int v = (tid < nb) ? partial[tid] : 0;
    lds[tid] = v;
    __syncthreads();
    for (int off = 1; off < 256; off <<= 1) {
        int t = (tid >= off) ? lds[tid - off] : 0;
        __syncthreads();
        lds[tid] += t;
        __syncthreads();
    }
    if (tid < nb) partial[tid] = lds[tid] - v;     // exclusive
    if (tid == nb - 1) *offs_n = lds[tid];         // grand total (== E)
}

// ---------- scan phase C: per-chunk exclusive scan + chunk offset -> offs, cursor ----------
__global__ void scanC_kernel(const int* __restrict__ counts, const int* __restrict__ partial,
                             int* __restrict__ offs, int* __restrict__ cursor, int n) {
    __shared__ int lds[256];
    int tid = threadIdx.x;
    int i0 = blockIdx.x * SCHUNK + tid * 4;
    int4 c4 = make_int4(0, 0, 0, 0);
    if (i0 + 3 < n) {
        c4 = *reinterpret_cast<const int4*>(counts + i0);
    } else {
        if (i0 + 0 < n) c4.x = counts[i0 + 0];
        if (i0 + 1 < n) c4.y = counts[i0 + 1];
        if (i0 + 2 < n) c4.z = counts[i0 + 2];
        if (i0 + 3 < n) c4.w = counts[i0 + 3];
    }
    int tsum = c4.x + c4.y + c4.z + c4.w;
    lds[tid] = tsum;
    __syncthreads();
    for (int off = 1; off < 256; off <<= 1) {
        int t = (tid >= off) ? lds[tid - off] : 0;
        __syncthreads();
        lds[tid] += t;
        __syncthreads();
    }
    int run = partial[blockIdx.x] + lds[tid] - tsum;
    int o0 = run, o1 = o0 + c4.x, o2 = o1 + c4.y, o3 = o2 + c4.z;
    if (i0 + 0 < n) { offs[i0 + 0] = o0; cursor[i0 + 0] = o0; }
    if (i0 + 1 < n) { offs[i0 + 1] = o1; cursor[i0 + 1] = o1; }
    if (i0 + 2 < n) { offs[i0 + 2] = o2; cursor[i0 + 2] = o2; }
    if (i0 + 3 < n) { offs[i0 + 3] = o3; cursor[i0 + 3] = o3; }
}

// ---------- fill CSR: packed (row, norm) bucketed by col ----------
__global__ void fill_kernel(const int* __restrict__ ei, const float* __restrict__ w,
                            const float* __restrict__ dis, int* __restrict__ cursor,
                            int2* __restrict__ centry, int E) {
    int e = blockIdx.x * blockDim.x + threadIdx.x;
    if (e >= E) return;
    int r = ei[e], c = ei[E + e];
    float nw = dis[r] * w[e] * dis[c];
    int pos = atomicAdd(&cursor[c], 1);
    centry[pos] = make_int2(r, __float_as_int(nw));
}

// ---------- small GEMM: Hout[N,32] = bn?(X)[N,FIN] @ W[FIN,32]; zeroes stats ----------
template <int FIN, bool BN>
__global__ void gemm_kernel(const float* __restrict__ X, const float* __restrict__ W,
                            const float* __restrict__ sc, float* __restrict__ Hout,
                            float* __restrict__ stats, int n) {
    __shared__ float Wl[FIN * HD];
    __shared__ float scl[64];
    for (int i = threadIdx.x; i < FIN * HD; i += blockDim.x) Wl[i] = W[i];
    if (BN && threadIdx.x < 64) scl[threadIdx.x] = sc[threadIdx.x];
    if (blockIdx.x == 0 && threadIdx.x < 64) stats[threadIdx.x] = 0.0f;
    __syncthreads();
    int idx = blockIdx.x * blockDim.x + threadIdx.x;
    if (idx >= n * HD) return;
    int node = idx >> 5, h = idx & 31;
    const float4* xr4 = reinterpret_cast<const float4*>(X + (size_t)node * FIN);
    float acc = 0.0f;
#pragma unroll
    for (int q = 0; q < FIN / 4; q++) {
        float4 v4 = xr4[q];
        float vs[4] = {v4.x, v4.y, v4.z, v4.w};
#pragma unroll
        for (int j = 0; j < 4; j++) {
            int k = q * 4 + j;
            float v = vs[j];
            if (BN) v = v * scl[k] + scl[32 + k];
            acc += v * Wl[k * HD + h];
        }
    }
    Hout[idx] = acc;
}

// ---------- aggregate: y[c] = relu(b + sum_{e:col==c} hlin[row]*norm + hlin[c]*dis[c]^2)
// one wave per node batch (32 lanes = feature dim, 2 edges in flight), + BN stats ----------
__global__ void agg_kernel(const float* __restrict__ hlin, const int* __restrict__ offs,
                           const int2* __restrict__ centry, const float* __restrict__ dis,
                           const float* __restrict__ bias, float* __restrict__ y,
                           float* __restrict__ stats, int n) {
    int wave = threadIdx.x >> 6, lane = threadIdx.x & 63, sub = lane >> 5, h = lane & 31;
    float bv = bias[h];
    float lsum = 0.0f, lsq = 0.0f;
    int base = (blockIdx.x * 4 + wave) * NODES_PER_WAVE;
    for (int t = 0; t < NODES_PER_WAVE; t++) {
        int node = base + t;
        if (node < n) {
            int s = offs[node], e2 = offs[node + 1];
            float acc = 0.0f;
            if (sub == 0) {
                float d = dis[node];
                acc = hlin[(size_t)node * HD + h] * d * d;   // self-loop
            }
            int j = s + sub;
            if (j < e2) {
                int2 ce = centry[j];
                j += 2;
                while (j < e2) {
                    int2 nx = centry[j];                     // prefetch next entry
                    acc += hlin[(size_t)ce.x * HD + h] * __int_as_float(ce.y);
                    ce = nx; j += 2;
                }
                acc += hlin[(size_t)ce.x * HD + h] * __int_as_float(ce.y);
            }
            acc += __shfl_xor(acc, 32, 64);
            float yv = fmaxf(acc + bv, 0.0f);
            if (sub == 0) {
                y[(size_t)node * HD + h] = yv;
                lsum += yv; lsq += yv * yv;
            }
        }
    }
    __shared__ float ls[4][32], lq[4][32];
    if (sub == 0) { ls[wave][h] = lsum; lq[wave][h] = lsq; }
    __syncthreads();
    if (threadIdx.x < 32) {
        float a = ls[0][threadIdx.x] + ls[1][threadIdx.x] + ls[2][threadIdx.x] + ls[3][threadIdx.x];
        float b = lq[0][threadIdx.x] + lq[1][threadIdx.x] + lq[2][threadIdx.x] + lq[3][threadIdx.x];
        atomicAdd(&stats[threadIdx.x], a);
        atomicAdd(&stats[32 + threadIdx.x], b);
    }
}

// ---------- BN params: scale/shift from sums ----------
__global__ void bnparam_kernel(const float* __restrict__ stats, const float* __restrict__ g,
                               const float* __restrict__ be, float* __restrict__ sc, int n) {
    int h = threadIdx.x;
    if (h >= HD) return;
    float invn = 1.0f / (float)n;
    float mean = stats[h] * invn;
    float var = stats[32 + h] * invn - mean * mean;   // biased variance
    float inv = rsqrtf(var + BN_EPS);
    float scale = inv * g[h];
    sc[h] = scale;
    sc[32 + h] = be[h] - mean * scale;
}

// ---------- final linear: bn(y1..3) concat [N,96] @ [96,2] + bl ----------
__global__ void final_kernel(const float* __restrict__ y1, const float* __restrict__ y2,
                             const float* __restrict__ y3, const float* __restrict__ sc1,
                             const float* __restrict__ sc2, const float* __restrict__ sc3,
                             const float* __restrict__ Wl, const float* __restrict__ bl,
                             float* __restrict__ out, int n) {
    __shared__ float Ws[96 * NCLS];
    __shared__ float scs[3][64];
    __shared__ float bs[NCLS];
    for (int i = threadIdx.x; i < 96 * NCLS; i += blockDim.x) Ws[i] = Wl[i];
    if (threadIdx.x < 64) {
        scs[0][threadIdx.x] = sc1[threadIdx.x];
        scs[1][threadIdx.x] = sc2[threadIdx.x];
        scs[2][threadIdx.x] = sc3[threadIdx.x];
    }
    if (threadIdx.x < NCLS) bs[threadIdx.x] = bl[threadIdx.x];
    __syncthreads();
    int i = blockIdx.x * blockDim.x + threadIdx.x;
    if (i >= n) return;
    float a0 = bs[0], a1 = bs[1];
    const float* ys[3] = {y1 + (size_t)i * HD, y2 + (size_t)i * HD, y3 + (size_t)i * HD};
#pragma unroll
    for (int L = 0; L < 3; L++) {
        const float4* r4 = reinterpret_cast<const float4*>(ys[L]);
#pragma unroll
        for (int q = 0; q < HD / 4; q++) {
            float4 v4 = r4[q];
            float vs[4] = {v4.x, v4.y, v4.z, v4.w};
#pragma unroll
            for (int j = 0; j < 4; j++) {
                int h = q * 4 + j;
                float v = vs[j] * scs[L][h] + scs[L][32 + h];
                a0 += v * Ws[(L * 32 + h) * 2];
                a1 += v * Ws[(L * 32 + h) * 2 + 1];
            }
        }
    }
    out[(size_t)i * 2] = a0;
    out[(size_t)i * 2 + 1] = a1;
}

extern "C" void kernel_launch(void* const* d_in, const int* in_sizes, int n_in,
                              void* d_out, int out_size, void* d_ws, size_t ws_size,
                              hipStream_t stream) {
    const float* x  = (const float*)d_in[0];
    const int*   ei = (const int*)d_in[1];
    const float* ew = (const float*)d_in[2];
    const float* W1 = (const float*)d_in[3];  const float* b1  = (const float*)d_in[4];
    const float* g1 = (const float*)d_in[5];  const float* be1 = (const float*)d_in[6];
    const float* W2 = (const float*)d_in[7];  const float* b2  = (const float*)d_in[8];
    const float* g2 = (const float*)d_in[9];  const float* be2 = (const float*)d_in[10];
    const float* W3 = (const float*)d_in[11]; const float* b3  = (const float*)d_in[12];
    const float* g3 = (const float*)d_in[13]; const float* be3 = (const float*)d_in[14];
    const float* Wl = (const float*)d_in[15]; const float* bl  = (const float*)d_in[16];

    int n = in_sizes[0] / F_IN;
    int E = in_sizes[1] / 2;

    char* ws = (char*)d_ws;
    auto alloc = [&](size_t bytes) -> char* {
        char* p = ws;
        ws += (bytes + 255) / 256 * 256;
        return p;
    };
    // deg + counts adjacent -> single memset
    char*  zreg   = alloc((size_t)2 * n * 4);
    float* deg    = (float*)zreg;
    int*   counts = (int*)(zreg + (size_t)n * 4);
    float* dis    = (float*)alloc((size_t)n * 4);
    int*   offs   = (int*)alloc((size_t)(n + 1) * 4);
    int*   cursor = (int*)alloc((size_t)n * 4);
    int*   partial= (int*)alloc(256 * 4);
    int2*  centry = (int2*)alloc((size_t)E * 8);
    float* hlin   = (float*)alloc((size_t)n * HD * 4);
    float* y1     = (float*)alloc((size_t)n * HD * 4);
    float* y2     = (float*)alloc((size_t)n * HD * 4);
    float* y3     = (float*)alloc((size_t)n * HD * 4);
    float* stats  = (float*)alloc(64 * 4);
    float* sc1    = (float*)alloc(64 * 4);
    float* sc2    = (float*)alloc(64 * 4);
    float* sc3    = (float*)alloc(64 * 4);

    hipMemsetAsync(zreg, 0, (size_t)2 * n * 4, stream);

    int eb  = (E + 255) / 256;
    int nb  = (n + 255) / 256;
    int nhb = (n * HD + 255) / 256;
    int scb = (n + SCHUNK - 1) / SCHUNK;                    // 98 for n=100000 (<=256 required)
    int aggb = (n + 4 * NODES_PER_WAVE - 1) / (4 * NODES_PER_WAVE);

    deg_hist_kernel<<<eb, 256, 0, stream>>>(ei, ew, deg, counts, E);
    scanA_kernel<<<scb, 256, 0, stream>>>(counts, deg, partial, dis, n);
    scanB_kernel<<<1, 256, 0, stream>>>(partial, scb, offs + n);
    scanC_kernel<<<scb, 256, 0, stream>>>(counts, partial, offs, cursor, n);
    fill_kernel<<<eb, 256, 0, stream>>>(ei, ew, dis, cursor, centry, E);

    // layer 1
    gemm_kernel<F_IN, false><<<nhb, 256, 0, stream>>>(x, W1, nullptr, hlin, stats, n);
    agg_kernel<<<aggb, 256, 0, stream>>>(hlin, offs, centry, dis, b1, y1, stats, n);
    bnparam_kernel<<<1, 32, 0, stream>>>(stats, g1, be1, sc1, n);
    // layer 2
    gemm_kernel<HD, true><<<nhb, 256, 0, stream>>>(y1, W2, sc1, hlin, stats, n);
    agg_kernel<<<aggb, 256, 0, stream>>>(hlin, offs, centry, dis, b2, y2, stats, n);
    bnparam_kernel<<<1, 32, 0, stream>>>(stats, g2, be2, sc2, n);
    // layer 3
    gemm_kernel<HD, true><<<nhb, 256, 0, stream>>>(y2, W3, sc2, hlin, stats, n);
    agg_kernel<<<aggb, 256, 0, stream>>>(hlin, offs, centry, dis, b3, y3, stats, n);
    bnparam_kernel<<<1, 32, 0, stream>>>(stats, g3, be3, sc3, n);

    final_kernel<<<nb, 256, 0, stream>>>(y1, y2, y3, sc1, sc2, sc3, Wl, bl, (float*)d_out, n);
}

// Round 3
// 544.943 us; speedup vs baseline: 1.6931x; 1.2855x over previous
//
#include <hip/hip_runtime.h>

#define F_IN 64
#define HD 32
#define NCLS 2
#define BN_EPS 1e-5f
#define SCHUNK 1024
#define NODES_PER_WAVE 16
#define FIX_SCALE 1073741824.0f            // 2^30
#define FIX_INV   9.313225746154785e-10f   // 2^-30
#define MASK40 ((1ULL << 40) - 1)

// ---------- fused histogram: one u64 atomic = count(hi24) + fixedpoint weighted deg(lo40) ----------
__global__ void hist64_kernel(const int* __restrict__ ei, const float* __restrict__ w,
                              unsigned long long* __restrict__ packed, int E) {
    int e = blockIdx.x * blockDim.x + threadIdx.x;
    if (e >= E) return;
    int c = ei[E + e];
    unsigned long long fx = (unsigned long long)(w[e] * FIX_SCALE + 0.5f);
    atomicAdd(&packed[c], (1ULL << 40) | fx);
}

// ---------- scan phase A: per-chunk counts-sums; fused dis = rsqrt(deg+1) ----------
__global__ void scanA_kernel(const unsigned long long* __restrict__ packed,
                             int* __restrict__ partial, float* __restrict__ dis, int n) {
    __shared__ int red[256];
    int base = blockIdx.x * SCHUNK;
    int tid = threadIdx.x;
    int s = 0;
    for (int i = tid; i < SCHUNK; i += 256) {
        int idx = base + i;
        if (idx < n) {
            unsigned long long p = packed[idx];
            s += (int)(p >> 40);
            float deg = (float)(p & MASK40) * FIX_INV;
            dis[idx] = rsqrtf(deg + 1.0f);   // self-loop weight 1; arg >= 1
        }
    }
    red[tid] = s;
    __syncthreads();
    for (int off = 128; off > 0; off >>= 1) {
        if (tid < off) red[tid] += red[tid + off];
        __syncthreads();
    }
    if (tid == 0) partial[blockIdx.x] = red[0];
}

// ---------- scan phase B: exclusive-scan the (<=256) partials; write total ----------
__global__ void scanB_kernel(int* __restrict__ partial, int nb, int* __restrict__ offs_n) {
    __shared__ int lds[256];
    int tid = threadIdx.x;
    int v = (tid < nb) ? partial[tid] : 0;
    lds[tid] = v;
    __syncthreads();
    for (int off = 1; off < 256; off <<= 1) {
        int t = (tid >= off) ? lds[tid - off] : 0;
        __syncthreads();
        lds[tid] += t;
        __syncthreads();
    }
    if (tid < nb) partial[tid] = lds[tid] - v;     // exclusive
    if (tid == nb - 1) *offs_n = lds[tid];         // grand total (== E)
}

// ---------- scan phase C: per-chunk exclusive scan + chunk offset -> offs, cursor ----------
__global__ void scanC_kernel(const unsigned long long* __restrict__ packed,
                             const int* __restrict__ partial,
                             int* __restrict__ offs, int* __restrict__ cursor, int n) {
    __shared__ int lds[256];
    int tid = threadIdx.x;
    int i0 = blockIdx.x * SCHUNK + tid * 4;
    int c0 = 0, c1 = 0, c2 = 0, c3 = 0;
    if (i0 + 0 < n) c0 = (int)(packed[i0 + 0] >> 40);
    if (i0 + 1 < n) c1 = (int)(packed[i0 + 1] >> 40);
    if (i0 + 2 < n) c2 = (int)(packed[i0 + 2] >> 40);
    if (i0 + 3 < n) c3 = (int)(packed[i0 + 3] >> 40);
    int tsum = c0 + c1 + c2 + c3;
    lds[tid] = tsum;
    __syncthreads();
    for (int off = 1; off < 256; off <<= 1) {
        int t = (tid >= off) ? lds[tid - off] : 0;
        __syncthreads();
        lds[tid] += t;
        __syncthreads();
    }
    int run = partial[blockIdx.x] + lds[tid] - tsum;
    int o0 = run, o1 = o0 + c0, o2 = o1 + c1, o3 = o2 + c2;
    if (i0 + 0 < n) { offs[i0 + 0] = o0; cursor[i0 + 0] = o0; }
    if (i0 + 1 < n) { offs[i0 + 1] = o1; cursor[i0 + 1] = o1; }
    if (i0 + 2 < n) { offs[i0 + 2] = o2; cursor[i0 + 2] = o2; }
    if (i0 + 3 < n) { offs[i0 + 3] = o3; cursor[i0 + 3] = o3; }
}

// ---------- fill CSR: packed (row, norm) bucketed by col ----------
__global__ void fill_kernel(const int* __restrict__ ei, const float* __restrict__ w,
                            const float* __restrict__ dis, int* __restrict__ cursor,
                            int2* __restrict__ centry, int E) {
    int e = blockIdx.x * blockDim.x + threadIdx.x;
    if (e >= E) return;
    int r = ei[e], c = ei[E + e];
    float nw = dis[r] * w[e] * dis[c];
    int pos = atomicAdd(&cursor[c], 1);
    centry[pos] = make_int2(r, __float_as_int(nw));
}

// ---------- small GEMM: Hout[N,32] = bn?(X)[N,FIN] @ W[FIN,32]
// BN scale/shift computed inline from statsPrev; zeroes statsCur (block 0) ----------
template <int FIN, bool BN>
__global__ void gemm_kernel(const float* __restrict__ X, const float* __restrict__ W,
                            const float* __restrict__ statsPrev, const float* __restrict__ g,
                            const float* __restrict__ be, float* __restrict__ Hout,
                            float* __restrict__ statsCur, int n) {
    __shared__ float Wl[FIN * HD];
    __shared__ float scl[64];
    for (int i = threadIdx.x; i < FIN * HD; i += blockDim.x) Wl[i] = W[i];
    if (BN && threadIdx.x < 32) {
        int h = threadIdx.x;
        float invn = 1.0f / (float)n;
        float mean = statsPrev[h] * invn;
        float var = statsPrev[32 + h] * invn - mean * mean;   // biased
        float sca = rsqrtf(var + BN_EPS) * g[h];
        scl[h] = sca;
        scl[32 + h] = be[h] - mean * sca;
    }
    if (blockIdx.x == 0 && threadIdx.x < 64) statsCur[threadIdx.x] = 0.0f;
    __syncthreads();
    int idx = blockIdx.x * blockDim.x + threadIdx.x;
    if (idx >= n * HD) return;
    int node = idx >> 5, h = idx & 31;
    const float4* xr4 = reinterpret_cast<const float4*>(X + (size_t)node * FIN);
    float acc = 0.0f;
#pragma unroll
    for (int q = 0; q < FIN / 4; q++) {
        float4 v4 = xr4[q];
        float vs[4] = {v4.x, v4.y, v4.z, v4.w};
#pragma unroll
        for (int j = 0; j < 4; j++) {
            int k = q * 4 + j;
            float v = vs[j];
            if (BN) v = v * scl[k] + scl[32 + k];
            acc += v * Wl[k * HD + h];
        }
    }
    Hout[idx] = acc;
}

// ---------- aggregate: y[c] = relu(b + sum_{e:col==c} hlin[row]*norm + hlin[c]*dis[c]^2)
// wave = 2 subs x 32 feature lanes; 2-wide unrolled gather (4 edges in flight/wave) ----------
__global__ void agg_kernel(const float* __restrict__ hlin, const int* __restrict__ offs,
                           const int2* __restrict__ centry, const float* __restrict__ dis,
                           const float* __restrict__ bias, float* __restrict__ y,
                           float* __restrict__ stats, int n) {
    int wave = threadIdx.x >> 6, lane = threadIdx.x & 63, sub = lane >> 5, h = lane & 31;
    float bv = bias[h];
    float lsum = 0.0f, lsq = 0.0f;
    int base = (blockIdx.x * 4 + wave) * NODES_PER_WAVE;
    for (int t = 0; t < NODES_PER_WAVE; t++) {
        int node = base + t;
        if (node < n) {
            int s = offs[node], e2 = offs[node + 1];
            float acc = 0.0f, acc2 = 0.0f;
            if (sub == 0) {
                float d = dis[node];
                acc = hlin[(size_t)node * HD + h] * d * d;   // self-loop
            }
            int j = s + sub;
            for (; j + 2 < e2; j += 4) {
                int2 a = centry[j];
                int2 b = centry[j + 2];
                acc  += hlin[(size_t)a.x * HD + h] * __int_as_float(a.y);
                acc2 += hlin[(size_t)b.x * HD + h] * __int_as_float(b.y);
            }
            if (j < e2) {
                int2 a = centry[j];
                acc += hlin[(size_t)a.x * HD + h] * __int_as_float(a.y);
            }
            acc += acc2;
            acc += __shfl_xor(acc, 32, 64);
            float yv = fmaxf(acc + bv, 0.0f);
            if (sub == 0) {
                y[(size_t)node * HD + h] = yv;
                lsum += yv; lsq += yv * yv;
            }
        }
    }
    __shared__ float ls[4][32], lq[4][32];
    if (sub == 0) { ls[wave][h] = lsum; lq[wave][h] = lsq; }
    __syncthreads();
    if (threadIdx.x < 32) {
        float a = ls[0][threadIdx.x] + ls[1][threadIdx.x] + ls[2][threadIdx.x] + ls[3][threadIdx.x];
        float b = lq[0][threadIdx.x] + lq[1][threadIdx.x] + lq[2][threadIdx.x] + lq[3][threadIdx.x];
        atomicAdd(&stats[threadIdx.x], a);
        atomicAdd(&stats[32 + threadIdx.x], b);
    }
}

// ---------- final linear: bn(y1..3) concat [N,96] @ [96,2] + bl; BN inline from stats ----------
__global__ void final_kernel(const float* __restrict__ y1, const float* __restrict__ y2,
                             const float* __restrict__ y3,
                             const float* __restrict__ s1, const float* __restrict__ s2,
                             const float* __restrict__ s3,
                             const float* __restrict__ g1, const float* __restrict__ be1,
                             const float* __restrict__ g2, const float* __restrict__ be2,
                             const float* __restrict__ g3, const float* __restrict__ be3,
                             const float* __restrict__ Wl, const float* __restrict__ bl,
                             float* __restrict__ out, int n) {
    __shared__ float Ws[96 * NCLS];
    __shared__ float scs[3][64];
    __shared__ float bs[NCLS];
    for (int i = threadIdx.x; i < 96 * NCLS; i += blockDim.x) Ws[i] = Wl[i];
    if (threadIdx.x < 96) {
        int L = threadIdx.x >> 5, h = threadIdx.x & 31;
        const float* st = (L == 0) ? s1 : (L == 1) ? s2 : s3;
        const float* gg = (L == 0) ? g1 : (L == 1) ? g2 : g3;
        const float* bb = (L == 0) ? be1 : (L == 1) ? be2 : be3;
        float invn = 1.0f / (float)n;
        float mean = st[h] * invn;
        float var = st[32 + h] * invn - mean * mean;
        float sca = rsqrtf(var + BN_EPS) * gg[h];
        scs[L][h] = sca;
        scs[L][32 + h] = bb[h] - mean * sca;
    }
    if (threadIdx.x < NCLS) bs[threadIdx.x] = bl[threadIdx.x];
    __syncthreads();
    int i = blockIdx.x * blockDim.x + threadIdx.x;
    if (i >= n) return;
    float a0 = bs[0], a1 = bs[1];
    const float* ys[3] = {y1 + (size_t)i * HD, y2 + (size_t)i * HD, y3 + (size_t)i * HD};
#pragma unroll
    for (int L = 0; L < 3; L++) {
        const float4* r4 = reinterpret_cast<const float4*>(ys[L]);
#pragma unroll
        for (int q = 0; q < HD / 4; q++) {
            float4 v4 = r4[q];
            float vs[4] = {v4.x, v4.y, v4.z, v4.w};
#pragma unroll
            for (int j = 0; j < 4; j++) {
                int h = q * 4 + j;
                float v = vs[j] * scs[L][h] + scs[L][32 + h];
                a0 += v * Ws[(L * 32 + h) * 2];
                a1 += v * Ws[(L * 32 + h) * 2 + 1];
            }
        }
    }
    out[(size_t)i * 2] = a0;
    out[(size_t)i * 2 + 1] = a1;
}

extern "C" void kernel_launch(void* const* d_in, const int* in_sizes, int n_in,
                              void* d_out, int out_size, void* d_ws, size_t ws_size,
                              hipStream_t stream) {
    const float* x  = (const float*)d_in[0];
    const int*   ei = (const int*)d_in[1];
    const float* ew = (const float*)d_in[2];
    const float* W1 = (const float*)d_in[3];  const float* b1  = (const float*)d_in[4];
    const float* g1 = (const float*)d_in[5];  const float* be1 = (const float*)d_in[6];
    const float* W2 = (const float*)d_in[7];  const float* b2  = (const float*)d_in[8];
    const float* g2 = (const float*)d_in[9];  const float* be2 = (const float*)d_in[10];
    const float* W3 = (const float*)d_in[11]; const float* b3  = (const float*)d_in[12];
    const float* g3 = (const float*)d_in[13]; const float* be3 = (const float*)d_in[14];
    const float* Wl = (const float*)d_in[15]; const float* bl  = (const float*)d_in[16];

    int n = in_sizes[0] / F_IN;
    int E = in_sizes[1] / 2;

    char* ws = (char*)d_ws;
    auto alloc = [&](size_t bytes) -> char* {
        char* p = ws;
        ws += (bytes + 255) / 256 * 256;
        return p;
    };
    unsigned long long* packed = (unsigned long long*)alloc((size_t)n * 8);
    float* dis    = (float*)alloc((size_t)n * 4);
    int*   offs   = (int*)alloc((size_t)(n + 1) * 4);
    int*   cursor = (int*)alloc((size_t)n * 4);
    int*   partial= (int*)alloc(256 * 4);
    int2*  centry = (int2*)alloc((size_t)E * 8);
    float* hlin   = (float*)alloc((size_t)n * HD * 4);
    float* y1     = (float*)alloc((size_t)n * HD * 4);
    float* y2     = (float*)alloc((size_t)n * HD * 4);
    float* y3     = (float*)alloc((size_t)n * HD * 4);
    float* stats1 = (float*)alloc(64 * 4);
    float* stats2 = (float*)alloc(64 * 4);
    float* stats3 = (float*)alloc(64 * 4);

    hipMemsetAsync(packed, 0, (size_t)n * 8, stream);

    int eb  = (E + 255) / 256;
    int nb  = (n + 255) / 256;
    int nhb = (n * HD + 255) / 256;
    int scb = (n + SCHUNK - 1) / SCHUNK;                    // 98 for n=100000 (<=256 required)
    int aggb = (n + 4 * NODES_PER_WAVE - 1) / (4 * NODES_PER_WAVE);

    hist64_kernel<<<eb, 256, 0, stream>>>(ei, ew, packed, E);
    scanA_kernel<<<scb, 256, 0, stream>>>(packed, partial, dis, n);
    scanB_kernel<<<1, 256, 0, stream>>>(partial, scb, offs + n);
    scanC_kernel<<<scb, 256, 0, stream>>>(packed, partial, offs, cursor, n);
    fill_kernel<<<eb, 256, 0, stream>>>(ei, ew, dis, cursor, centry, E);

    // layer 1
    gemm_kernel<F_IN, false><<<nhb, 256, 0, stream>>>(x, W1, nullptr, nullptr, nullptr, hlin, stats1, n);
    agg_kernel<<<aggb, 256, 0, stream>>>(hlin, offs, centry, dis, b1, y1, stats1, n);
    // layer 2
    gemm_kernel<HD, true><<<nhb, 256, 0, stream>>>(y1, W2, stats1, g1, be1, hlin, stats2, n);
    agg_kernel<<<aggb, 256, 0, stream>>>(hlin, offs, centry, dis, b2, y2, stats2, n);
    // layer 3
    gemm_kernel<HD, true><<<nhb, 256, 0, stream>>>(y2, W3, stats2, g2, be2, hlin, stats3, n);
    agg_kernel<<<aggb, 256, 0, stream>>>(hlin, offs, centry, dis, b3, y3, stats3, n);

    final_kernel<<<nb, 256, 0, stream>>>(y1, y2, y3, stats1, stats2, stats3,
                                         g1, be1, g2, be2, g3, be3, Wl, bl, (float*)d_out, n);
}

// Round 4
// 534.600 us; speedup vs baseline: 1.7259x; 1.0193x over previous
//
#include <hip/hip_runtime.h>

typedef unsigned int uint;
typedef unsigned short ushort;

#define F_IN 64
#define HD 32
#define NCLS 2
#define BN_EPS 1e-5f
#define SCHUNK 1024
#define NPW 8
#define FIX_SCALE 1073741824.0f            // 2^30
#define FIX_INV   9.313225746154785e-10f   // 2^-30
#define MASK40 ((1ULL << 40) - 1)

__device__ __forceinline__ ushort f2bf(float f) {
    uint u = __float_as_uint(f);
    u = (u + 0x7FFFu + ((u >> 16) & 1u)) >> 16;   // RNE
    return (ushort)u;
}
__device__ __forceinline__ float bf_lo(uint w) { return __uint_as_float(w << 16); }
__device__ __forceinline__ float bf_hi(uint w) { return __uint_as_float(w & 0xFFFF0000u); }

// ---------- fused histogram: u64 atomic = count(hi24)+fixedpoint deg(lo40); epos = rank ----------
__global__ void hist64_kernel(const int* __restrict__ ei, const float* __restrict__ w,
                              unsigned long long* __restrict__ packed,
                              ushort* __restrict__ epos, int E) {
    int e = blockIdx.x * blockDim.x + threadIdx.x;
    if (e >= E) return;
    int c = ei[E + e];
    unsigned long long fx = (unsigned long long)(w[e] * FIX_SCALE + 0.5f);
    unsigned long long old = atomicAdd(&packed[c], (1ULL << 40) | fx);
    epos[e] = (ushort)(old >> 40);
}

// ---------- scan phase A: per-chunk counts-sums; fused dis = rsqrt(deg+1) ----------
__global__ void scanA_kernel(const unsigned long long* __restrict__ packed,
                             int* __restrict__ partial, float* __restrict__ dis, int n) {
    __shared__ int red[256];
    int base = blockIdx.x * SCHUNK;
    int tid = threadIdx.x;
    int s = 0;
    for (int i = tid; i < SCHUNK; i += 256) {
        int idx = base + i;
        if (idx < n) {
            unsigned long long p = packed[idx];
            s += (int)(p >> 40);
            float deg = (float)(p & MASK40) * FIX_INV;
            dis[idx] = rsqrtf(deg + 1.0f);   // self-loop weight 1; arg >= 1
        }
    }
    red[tid] = s;
    __syncthreads();
    for (int off = 128; off > 0; off >>= 1) {
        if (tid < off) red[tid] += red[tid + off];
        __syncthreads();
    }
    if (tid == 0) partial[blockIdx.x] = red[0];
}

// ---------- scan phase B: exclusive-scan the (<=256) partials ----------
__global__ void scanB_kernel(int* __restrict__ partial, int nb, int* __restrict__ offs_n) {
    __shared__ int lds[256];
    int tid = threadIdx.x;
    int v = (tid < nb) ? partial[tid] : 0;
    lds[tid] = v;
    __syncthreads();
    for (int off = 1; off < 256; off <<= 1) {
        int t = (tid >= off) ? lds[tid - off] : 0;
        __syncthreads();
        lds[tid] += t;
        __syncthreads();
    }
    if (tid < nb) partial[tid] = lds[tid] - v;     // exclusive
    if (tid == nb - 1) *offs_n = lds[tid];         // grand total (== E)
}

// ---------- scan phase C: per-chunk exclusive scan + chunk offset -> offs ----------
__global__ void scanC_kernel(const unsigned long long* __restrict__ packed,
                             const int* __restrict__ partial,
                             int* __restrict__ offs, int n) {
    __shared__ int lds[256];
    int tid = threadIdx.x;
    int i0 = blockIdx.x * SCHUNK + tid * 4;
    int c0 = 0, c1 = 0, c2 = 0, c3 = 0;
    if (i0 + 0 < n) c0 = (int)(packed[i0 + 0] >> 40);
    if (i0 + 1 < n) c1 = (int)(packed[i0 + 1] >> 40);
    if (i0 + 2 < n) c2 = (int)(packed[i0 + 2] >> 40);
    if (i0 + 3 < n) c3 = (int)(packed[i0 + 3] >> 40);
    int tsum = c0 + c1 + c2 + c3;
    lds[tid] = tsum;
    __syncthreads();
    for (int off = 1; off < 256; off <<= 1) {
        int t = (tid >= off) ? lds[tid - off] : 0;
        __syncthreads();
        lds[tid] += t;
        __syncthreads();
    }
    int run = partial[blockIdx.x] + lds[tid] - tsum;
    int o0 = run, o1 = o0 + c0, o2 = o1 + c1, o3 = o2 + c2;
    if (i0 + 0 < n) offs[i0 + 0] = o0;
    if (i0 + 1 < n) offs[i0 + 1] = o1;
    if (i0 + 2 < n) offs[i0 + 2] = o2;
    if (i0 + 3 < n) offs[i0 + 3] = o3;
}

// ---------- fill CSR (atomic-free): pos = offs[col] + epos[e] ----------
__global__ void fill_kernel(const int* __restrict__ ei, const float* __restrict__ w,
                            const float* __restrict__ dis, const int* __restrict__ offs,
                            const ushort* __restrict__ epos,
                            int2* __restrict__ centry, int E) {
    int e = blockIdx.x * blockDim.x + threadIdx.x;
    if (e >= E) return;
    int r = ei[e], c = ei[E + e];
    float nw = dis[r] * w[e] * dis[c];
    int pos = offs[c] + (int)epos[e];
    centry[pos] = make_int2(r, __float_as_int(nw));
}

// ---------- small GEMM: Hbf[N,32](bf16) = bn?(X)[N,FIN] @ W[FIN,32]; zeroes statsCur ----------
template <int FIN, bool BN>
__global__ void gemm_kernel(const float* __restrict__ X, const float* __restrict__ W,
                            const float* __restrict__ statsPrev, const float* __restrict__ g,
                            const float* __restrict__ be, ushort* __restrict__ Hbf,
                            float* __restrict__ statsCur, int n) {
    __shared__ float Wl[FIN * HD];
    __shared__ float scl[64];
    for (int i = threadIdx.x; i < FIN * HD; i += blockDim.x) Wl[i] = W[i];
    if (BN && threadIdx.x < 32) {
        int h = threadIdx.x;
        float invn = 1.0f / (float)n;
        float mean = statsPrev[h] * invn;
        float var = statsPrev[32 + h] * invn - mean * mean;   // biased
        float sca = rsqrtf(var + BN_EPS) * g[h];
        scl[h] = sca;
        scl[32 + h] = be[h] - mean * sca;
    }
    if (blockIdx.x == 0 && threadIdx.x < 64) statsCur[threadIdx.x] = 0.0f;
    __syncthreads();
    int idx = blockIdx.x * blockDim.x + threadIdx.x;
    if (idx >= n * HD) return;
    int node = idx >> 5, h = idx & 31;
    const float4* xr4 = reinterpret_cast<const float4*>(X + (size_t)node * FIN);
    float acc = 0.0f;
#pragma unroll
    for (int q = 0; q < FIN / 4; q++) {
        float4 v4 = xr4[q];
        float vs[4] = {v4.x, v4.y, v4.z, v4.w};
#pragma unroll
        for (int j = 0; j < 4; j++) {
            int k = q * 4 + j;
            float v = vs[j];
            if (BN) v = v * scl[k] + scl[32 + k];
            acc += v * Wl[k * HD + h];
        }
    }
    Hbf[idx] = f2bf(acc);
}

// ---------- aggregate: y = relu(b + sum hbf[row]*norm + hbf[node]*dis^2), bf16 gather
// wave = 4 groups x 16 lanes; lane l holds features {2l, 2l+1}; 8 gathers in flight ----------
__global__ void agg_kernel(const uint* __restrict__ hlin, const int* __restrict__ offs,
                           const int2* __restrict__ centry, const float* __restrict__ dis,
                           const float* __restrict__ bias, float* __restrict__ y,
                           float* __restrict__ stats, int n) {
    int wave = threadIdx.x >> 6, lane = threadIdx.x & 63;
    int grp = lane >> 4, l = lane & 15;
    float b0 = bias[2 * l], b1 = bias[2 * l + 1];
    float s0 = 0.f, s1 = 0.f, q0 = 0.f, q1 = 0.f;
    int base = (blockIdx.x * 4 + wave) * NPW;
    for (int t = 0; t < NPW; t++) {
        int node = base + t;
        if (node >= n) break;                       // wave-uniform
        int s = offs[node], e2 = offs[node + 1];
        float a0 = 0.f, a1 = 0.f, c0 = 0.f, c1 = 0.f;
        if (grp == 0) {
            float d = dis[node];
            float dd = d * d;
            uint hv = hlin[(size_t)node * 16 + l];  // self-loop
            a0 = bf_lo(hv) * dd;
            a1 = bf_hi(hv) * dd;
        }
        int j = s + grp;
        for (; j + 4 < e2; j += 8) {
            int2 ea = centry[j];
            int2 eb = centry[j + 4];
            uint ha = hlin[(size_t)ea.x * 16 + l];
            uint hb = hlin[(size_t)eb.x * 16 + l];
            float wa = __int_as_float(ea.y), wb = __int_as_float(eb.y);
            a0 += bf_lo(ha) * wa; a1 += bf_hi(ha) * wa;
            c0 += bf_lo(hb) * wb; c1 += bf_hi(hb) * wb;
        }
        if (j < e2) {
            int2 ea = centry[j];
            uint ha = hlin[(size_t)ea.x * 16 + l];
            float wa = __int_as_float(ea.y);
            a0 += bf_lo(ha) * wa; a1 += bf_hi(ha) * wa;
        }
        a0 += c0; a1 += c1;
        a0 += __shfl_xor(a0, 16, 64); a1 += __shfl_xor(a1, 16, 64);
        a0 += __shfl_xor(a0, 32, 64); a1 += __shfl_xor(a1, 32, 64);
        float y0 = fmaxf(a0 + b0, 0.f), y1 = fmaxf(a1 + b1, 0.f);
        if (grp == 0) {
            *reinterpret_cast<float2*>(&y[(size_t)node * HD + 2 * l]) = make_float2(y0, y1);
            s0 += y0; s1 += y1; q0 += y0 * y0; q1 += y1 * y1;
        }
    }
    __shared__ float ls[4][32], lq[4][32];
    if (grp == 0) {
        ls[wave][2 * l] = s0; ls[wave][2 * l + 1] = s1;
        lq[wave][2 * l] = q0; lq[wave][2 * l + 1] = q1;
    }
    __syncthreads();
    if (threadIdx.x < 32) {
        float a = ls[0][threadIdx.x] + ls[1][threadIdx.x] + ls[2][threadIdx.x] + ls[3][threadIdx.x];
        float b = lq[0][threadIdx.x] + lq[1][threadIdx.x] + lq[2][threadIdx.x] + lq[3][threadIdx.x];
        atomicAdd(&stats[threadIdx.x], a);
        atomicAdd(&stats[32 + threadIdx.x], b);
    }
}

// ---------- final linear: bn(y1..3) concat [N,96] @ [96,2] + bl; BN inline from stats ----------
__global__ void final_kernel(const float* __restrict__ y1, const float* __restrict__ y2,
                             const float* __restrict__ y3,
                             const float* __restrict__ s1, const float* __restrict__ s2,
                             const float* __restrict__ s3,
                             const float* __restrict__ g1, const float* __restrict__ be1,
                             const float* __restrict__ g2, const float* __restrict__ be2,
                             const float* __restrict__ g3, const float* __restrict__ be3,
                             const float* __restrict__ Wl, const float* __restrict__ bl,
                             float* __restrict__ out, int n) {
    __shared__ float Ws[96 * NCLS];
    __shared__ float scs[3][64];
    __shared__ float bs[NCLS];
    for (int i = threadIdx.x; i < 96 * NCLS; i += blockDim.x) Ws[i] = Wl[i];
    if (threadIdx.x < 96) {
        int L = threadIdx.x >> 5, h = threadIdx.x & 31;
        const float* st = (L == 0) ? s1 : (L == 1) ? s2 : s3;
        const float* gg = (L == 0) ? g1 : (L == 1) ? g2 : g3;
        const float* bb = (L == 0) ? be1 : (L == 1) ? be2 : be3;
        float invn = 1.0f / (float)n;
        float mean = st[h] * invn;
        float var = st[32 + h] * invn - mean * mean;
        float sca = rsqrtf(var + BN_EPS) * gg[h];
        scs[L][h] = sca;
        scs[L][32 + h] = bb[h] - mean * sca;
    }
    if (threadIdx.x < NCLS) bs[threadIdx.x] = bl[threadIdx.x];
    __syncthreads();
    int i = blockIdx.x * blockDim.x + threadIdx.x;
    if (i >= n) return;
    float a0 = bs[0], a1 = bs[1];
    const float* ys[3] = {y1 + (size_t)i * HD, y2 + (size_t)i * HD, y3 + (size_t)i * HD};
#pragma unroll
    for (int L = 0; L < 3; L++) {
        const float4* r4 = reinterpret_cast<const float4*>(ys[L]);
#pragma unroll
        for (int q = 0; q < HD / 4; q++) {
            float4 v4 = r4[q];
            float vs[4] = {v4.x, v4.y, v4.z, v4.w};
#pragma unroll
            for (int j = 0; j < 4; j++) {
                int h = q * 4 + j;
                float v = vs[j] * scs[L][h] + scs[L][32 + h];
                a0 += v * Ws[(L * 32 + h) * 2];
                a1 += v * Ws[(L * 32 + h) * 2 + 1];
            }
        }
    }
    out[(size_t)i * 2] = a0;
    out[(size_t)i * 2 + 1] = a1;
}

extern "C" void kernel_launch(void* const* d_in, const int* in_sizes, int n_in,
                              void* d_out, int out_size, void* d_ws, size_t ws_size,
                              hipStream_t stream) {
    const float* x  = (const float*)d_in[0];
    const int*   ei = (const int*)d_in[1];
    const float* ew = (const float*)d_in[2];
    const float* W1 = (const float*)d_in[3];  const float* b1  = (const float*)d_in[4];
    const float* g1 = (const float*)d_in[5];  const float* be1 = (const float*)d_in[6];
    const float* W2 = (const float*)d_in[7];  const float* b2  = (const float*)d_in[8];
    const float* g2 = (const float*)d_in[9];  const float* be2 = (const float*)d_in[10];
    const float* W3 = (const float*)d_in[11]; const float* b3  = (const float*)d_in[12];
    const float* g3 = (const float*)d_in[13]; const float* be3 = (const float*)d_in[14];
    const float* Wl = (const float*)d_in[15]; const float* bl  = (const float*)d_in[16];

    int n = in_sizes[0] / F_IN;
    int E = in_sizes[1] / 2;

    char* ws = (char*)d_ws;
    auto alloc = [&](size_t bytes) -> char* {
        char* p = ws;
        ws += (bytes + 255) / 256 * 256;
        return p;
    };
    unsigned long long* packed = (unsigned long long*)alloc((size_t)n * 8);
    float*  dis    = (float*)alloc((size_t)n * 4);
    int*    offs   = (int*)alloc((size_t)(n + 1) * 4);
    int*    partial= (int*)alloc(256 * 4);
    ushort* epos   = (ushort*)alloc((size_t)E * 2);
    int2*   centry = (int2*)alloc((size_t)E * 8);
    ushort* hlin   = (ushort*)alloc((size_t)n * HD * 2);
    float*  y1     = (float*)alloc((size_t)n * HD * 4);
    float*  y2     = (float*)alloc((size_t)n * HD * 4);
    float*  y3     = (float*)alloc((size_t)n * HD * 4);
    float*  stats1 = (float*)alloc(64 * 4);
    float*  stats2 = (float*)alloc(64 * 4);
    float*  stats3 = (float*)alloc(64 * 4);

    hipMemsetAsync(packed, 0, (size_t)n * 8, stream);

    int eb  = (E + 255) / 256;
    int nb  = (n + 255) / 256;
    int nhb = (n * HD + 255) / 256;
    int scb = (n + SCHUNK - 1) / SCHUNK;            // 98 for n=100000 (<=256 required)
    int aggb = (n + 4 * NPW - 1) / (4 * NPW);

    hist64_kernel<<<eb, 256, 0, stream>>>(ei, ew, packed, epos, E);
    scanA_kernel<<<scb, 256, 0, stream>>>(packed, partial, dis, n);
    scanB_kernel<<<1, 256, 0, stream>>>(partial, scb, offs + n);
    scanC_kernel<<<scb, 256, 0, stream>>>(packed, partial, offs, n);
    fill_kernel<<<eb, 256, 0, stream>>>(ei, ew, dis, offs, epos, centry, E);

    // layer 1
    gemm_kernel<F_IN, false><<<nhb, 256, 0, stream>>>(x, W1, nullptr, nullptr, nullptr, hlin, stats1, n);
    agg_kernel<<<aggb, 256, 0, stream>>>((const uint*)hlin, offs, centry, dis, b1, y1, stats1, n);
    // layer 2
    gemm_kernel<HD, true><<<nhb, 256, 0, stream>>>(y1, W2, stats1, g1, be1, hlin, stats2, n);
    agg_kernel<<<aggb, 256, 0, stream>>>((const uint*)hlin, offs, centry, dis, b2, y2, stats2, n);
    // layer 3
    gemm_kernel<HD, true><<<nhb, 256, 0, stream>>>(y2, W3, stats2, g2, be2, hlin, stats3, n);
    agg_kernel<<<aggb, 256, 0, stream>>>((const uint*)hlin, offs, centry, dis, b3, y3, stats3, n);

    final_kernel<<<nb, 256, 0, stream>>>(y1, y2, y3, stats1, stats2, stats3,
                                         g1, be1, g2, be2, g3, be3, Wl, bl, (float*)d_out, n);
}